// Round 8
// baseline (719.015 us; speedup 1.0000x reference)
//
#include <hip/hip_runtime.h>
#include <hip/hip_fp16.h>
#include <cstdint>
#include <cstddef>

#define BB 8
#define NSPX 1024
#define NNODE 8192      // BB*NSPX
#define EE 131072
#define NPIX 524288     // BB*256*256
#define CH 256

typedef unsigned int uint;
typedef unsigned long long u64;

__device__ __forceinline__ uint packh2(float a, float b) {
  __half2 h = __float22half2_rn(make_float2(a, b));
  return *reinterpret_cast<uint*>(&h);
}
__device__ __forceinline__ __half2 uh2(uint u) { return *reinterpret_cast<__half2*>(&u); }
__device__ __forceinline__ uint h2u(__half2 h) { return *reinterpret_cast<uint*>(&h); }

// ---------------- zero workspace accumulators ----------------
__global__ __launch_bounds__(256) void zero_kernel(int4* p, int n4) {
  int i = blockIdx.x * 256 + threadIdx.x;
  int stride = gridDim.x * 256;
  int4 z = make_int4(0, 0, 0, 0);
  for (; i < n4; i += stride) p[i] = z;
}

// ---------------- cnt2: seg ids + packed(cnt,h,w) atomics | edge dst counting ----------------
__global__ __launch_bounds__(256) void cnt2_kernel(const int* __restrict__ labels,
                                                   const int* __restrict__ edst,
                                                   int* __restrict__ segb,
                                                   u64* __restrict__ packed,
                                                   int* __restrict__ cnt_e) {
  int blk = blockIdx.x;
  int t = threadIdx.x;
  if (blk < 2048) {
    int p = blk * 256 + t;
    int b = p >> 16;
    int h = (p >> 8) & 255;
    int w = p & 255;
    int seg = labels[p] + (b << 10);
    segb[p] = seg;
    u64 enc = (1ULL << 48) | ((u64)h << 24) | (u64)w;
    atomicAdd(&packed[seg], enc);
  } else {
    int e = (blk - 2048) * 256 + t;
    atomicAdd(&cnt_e[edst[e]], 1);
  }
}

// ---------------- FUSED-B: dual scan (blocks 0-1) || rcnt/centroids (blocks 2-9) ----------------
__global__ __launch_bounds__(1024) void fusedB_kernel(const u64* __restrict__ packed,
                                                      const int* __restrict__ cnt_e,
                                                      int* __restrict__ poff, int* __restrict__ eoff,
                                                      float* __restrict__ rcnt,
                                                      float* __restrict__ pch, float* __restrict__ pcw) {
  int blk = blockIdx.x;
  int t = threadIdx.x;
  if (blk < 2) {
    __shared__ int ps[1024];
    int which = blk;
    int* coff = which ? eoff : poff;
    int base = t * 8;
    int v[8];
    int sum = 0;
#pragma unroll
    for (int i = 0; i < 8; ++i) {
      int x = which ? cnt_e[base + i] : (int)(packed[base + i] >> 48);
      v[i] = sum;
      sum += x;
    }
    ps[t] = sum;
    __syncthreads();
    for (int off = 1; off < 1024; off <<= 1) {
      int x = (t >= off) ? ps[t - off] : 0;
      __syncthreads();
      ps[t] += x;
      __syncthreads();
    }
    int prev = (t == 0) ? 0 : ps[t - 1];
#pragma unroll
    for (int i = 0; i < 8; ++i) coff[base + i] = prev + v[i];
    if (t == 1023) coff[8192] = ps[1023];
  } else {
    int n = (blk - 2) * 1024 + t;
    u64 v = packed[n];
    int c = (int)(v >> 48);
    int sh = (int)((v >> 24) & 0xFFFFFF);
    int sw = (int)(v & 0xFFFFFF);
    float r = 1.0f / (float)(c > 1 ? c : 1);
    rcnt[n] = r;
    pch[n] = (float)sh * r * (1.0f / 255.0f);
    pcw[n] = (float)sw * r * (1.0f / 255.0f);
  }
}

// ---------------- device: transpose [B,256,P] -> [B,P,256] f16, FULL 256ch x 64px tile ----
// One block writes 64 COMPLETE pixel rows: 64 x 512 B = 32 KB fully contiguous HBM writes
// (previous variants wrote 128 B chunks per pixel from 4 different blocks -> 4x page opens,
// ~1.3 TB/s write ceiling -- the invariant across all ~150 us transpose attempts).
// Reads: 256 B per channel row (proven pattern-insensitive by R6==R7 A/B).
// LDS 256 x 33 uints = 33 KB -> 4 blocks/CU. 8-way bank conflict on the LDS read phase is
// ~1 us total -- ignored.
__device__ __forceinline__ void dev_transpose_full(const float* __restrict__ src, __half* __restrict__ dst,
                                                   int P, int b, int p0, int t,
                                                   uint (*tile)[33]) {
  int l16 = t & 15, r16 = t >> 4;
#pragma unroll
  for (int pass = 0; pass < 16; ++pass) {
    int c = pass * 16 + r16;
    float4 v = *(const float4*)&src[((size_t)b * 256 + c) * P + p0 + l16 * 4];
    tile[c][l16 * 2]     = packh2(v.x, v.y);   // pixels (p, p+1) of channel c
    tile[c][l16 * 2 + 1] = packh2(v.z, v.w);
  }
  __syncthreads();
  int q = t & 31, r8 = t >> 5;
#pragma unroll
  for (int pass = 0; pass < 8; ++pass) {
    int p = pass * 8 + r8;
    int ph = p >> 1;
    int odd = p & 1;
    uint r[4];
#pragma unroll
    for (int j = 0; j < 4; ++j) {
      uint ua = tile[q * 8 + 2 * j][ph];       // channels 8q+2j, pixels (2ph, 2ph+1)
      uint ub = tile[q * 8 + 2 * j + 1][ph];   // channel 8q+2j+1
      r[j] = odd ? ((ua >> 16) | (ub & 0xFFFF0000u))
                 : ((ua & 0xFFFFu) | (ub << 16));
    }
    *(uint4*)&dst[((size_t)b * P + p0 + p) * 256 + q * 8] = make_uint4(r[0], r[1], r[2], r[3]);
  }
}

// ---------------- T2K: skip2 transpose (2048 blocks) + skip1 transpose (512 blocks) ----------
__global__ __launch_bounds__(256) void t2k_kernel(const float* __restrict__ skip2, __half* __restrict__ F2t,
                                                  const float* __restrict__ skip1, __half* __restrict__ F1t) {
  __shared__ uint tile[256][33];   // 33 KB
  int idx = blockIdx.x;
  int t = threadIdx.x;
  if (idx < 2048) {
    int p0 = (idx & 255) * 64;
    int b = idx >> 8;
    dev_transpose_full(skip2, F2t, 16384, b, p0, t, tile);
  } else {
    int i2 = idx - 2048;               // 0..511
    int p0 = (i2 & 63) * 64;
    int b = i2 >> 6;
    dev_transpose_full(skip1, F1t, 4096, b, p0, t, tile);
  }
}

// ---------------- device: skip0 fold out[b][m][n] = sum_k skip0[b][k][m]*W0[k][n], f16 out ----
__device__ __forceinline__ void dev_gemm_kmaj(const float* __restrict__ A, const float* __restrict__ W,
                                              __half* __restrict__ out, int idx, int t,
                                              float (*As)[36]) {
  int b = idx >> 6;
  int m0 = (idx & 31) * 32;
  int n0 = ((idx >> 5) & 1) * 128;
  int ct = t & 31;
  int rm = t >> 5;
  int l8 = t & 7, kr = t >> 3;
  const float* Ab = A + (size_t)b * 512 * 1024;
  float4 acc[4];
#pragma unroll
  for (int i = 0; i < 4; ++i) acc[i] = make_float4(0.f, 0.f, 0.f, 0.f);
  for (int k0 = 0; k0 < 512; k0 += 64) {
#pragma unroll
    for (int pass = 0; pass < 2; ++pass) {
      int k = kr + pass * 32;
      float4 v = *(const float4*)&Ab[(size_t)(k0 + k) * 1024 + m0 + l8 * 4];
      *(float4*)&As[k][l8 * 4] = v;
    }
    __syncthreads();
#pragma unroll 8
    for (int k = 0; k < 64; ++k) {
      float4 a = *(const float4*)&As[k][rm * 4];
      float4 wv = *(const float4*)&W[(size_t)(k0 + k) * 256 + n0 + ct * 4];
      acc[0].x += a.x * wv.x; acc[0].y += a.x * wv.y; acc[0].z += a.x * wv.z; acc[0].w += a.x * wv.w;
      acc[1].x += a.y * wv.x; acc[1].y += a.y * wv.y; acc[1].z += a.y * wv.z; acc[1].w += a.y * wv.w;
      acc[2].x += a.z * wv.x; acc[2].y += a.z * wv.y; acc[2].z += a.z * wv.z; acc[2].w += a.z * wv.w;
      acc[3].x += a.w * wv.x; acc[3].y += a.w * wv.y; acc[3].z += a.w * wv.z; acc[3].w += a.w * wv.w;
    }
    __syncthreads();
  }
#pragma unroll
  for (int i = 0; i < 4; ++i) {
    int m = m0 + rm * 4 + i;
    uint2 pk = make_uint2(packh2(acc[i].x, acc[i].y), packh2(acc[i].z, acc[i].w));
    *(uint2*)&out[((size_t)b * 1024 + m) * 256 + n0 + ct * 4] = pk;
  }
}

// ---------------- FUSED-S: scatter2 (2560 blocks) || gemm_kmaj (512 blocks) ----------------
__global__ __launch_bounds__(256) void fusedS_kernel(const float* __restrict__ skip0,
                                                     const float* __restrict__ W0,
                                                     __half* __restrict__ F0b,
                                                     const int* __restrict__ segb,
                                                     const int* __restrict__ poff,
                                                     int* __restrict__ pcur,
                                                     int* __restrict__ psorted,
                                                     const int* __restrict__ esrc,
                                                     const int* __restrict__ edst,
                                                     const float* __restrict__ pch,
                                                     const float* __restrict__ pcw,
                                                     const int* __restrict__ eoff,
                                                     int* __restrict__ ecur,
                                                     uint2* __restrict__ evw,
                                                     float* __restrict__ outp) {
  __shared__ __align__(16) float As[64][36];
  int blk = blockIdx.x;
  int t = threadIdx.x;
  if (blk >= 2560) {
    dev_gemm_kmaj(skip0, W0, F0b, blk - 2560, t, As);
    return;
  }
  if (blk < 2048) {
    int p = blk * 256 + t;
    int sg = segb[p];
    int pos = poff[sg] + atomicAdd(&pcur[sg], 1);
    psorted[pos] = p;
  } else {
    int e = (blk - 2048) * 256 + t;
    int s1 = esrc[e], d1 = edst[e];
    float dh = pch[s1] - pch[d1];
    float dw = pcw[s1] - pcw[d1];
    float ea = expf(-(dh * dh + dw * dw) * 20.0f);
    outp[2 * EE + e] = ea;
    int pos = eoff[d1] + atomicAdd(&ecur[d1], 1);
    evw[pos] = make_uint2((uint)s1, __float_as_uint(ea));
  }
}

// ---------------- gather pooling: packed-f16 tap accumulate (16 ch / lane) ----------------
__device__ __forceinline__ void tap16(const __half* __restrict__ tp, float wt, __half2* acc) {
  uint4 qa = *(const uint4*)tp;
  uint4 qb = *(const uint4*)(tp + 8);
  __half2 W = __float2half2_rn(wt);
  acc[0] = __hfma2(W, uh2(qa.x), acc[0]);
  acc[1] = __hfma2(W, uh2(qa.y), acc[1]);
  acc[2] = __hfma2(W, uh2(qa.z), acc[2]);
  acc[3] = __hfma2(W, uh2(qa.w), acc[3]);
  acc[4] = __hfma2(W, uh2(qb.x), acc[4]);
  acc[5] = __hfma2(W, uh2(qb.y), acc[5]);
  acc[6] = __hfma2(W, uh2(qb.z), acc[6]);
  acc[7] = __hfma2(W, uh2(qb.w), acc[7]);
}

template <int HS>
__device__ __forceinline__ void taps16(const __half* __restrict__ fb, int h, int w, __half2* acc) {
  const float fh = (float)(HS - 1) / 255.0f;
  float ph = h * fh, pw = w * fh;
  int i0 = (int)ph, j0 = (int)pw;
  float th = ph - (float)i0, tw = pw - (float)j0;
  int i1 = min(i0 + 1, HS - 1), jj1 = min(j0 + 1, HS - 1);
  float w11 = th * tw, w10 = th - w11, w01 = tw - w11, w00 = 1.f - th - tw + w11;
  tap16(fb + (i0 * HS + j0) * 256, w00, acc);
  tap16(fb + (i0 * HS + jj1) * 256, w01, acc);
  tap16(fb + (i1 * HS + j0) * 256, w10, acc);
  tap16(fb + (i1 * HS + jj1) * 256, w11, acc);
}

// ---------------- FUSED-C: gather2(half0) -> gather01 -> gather2(half1) ----------------
__global__ __launch_bounds__(256) void fusedC_kernel(const __half* __restrict__ F0,
                                                     const __half* __restrict__ F1,
                                                     const __half* __restrict__ F2,
                                                     const int* __restrict__ poff,
                                                     const int* __restrict__ psorted,
                                                     const float* __restrict__ rc,
                                                     __half* __restrict__ p0out,
                                                     float* __restrict__ p1out,
                                                     float* __restrict__ p2out) {
  __shared__ __align__(16) char smem[18432];
  int blk = blockIdx.x;
  int t = threadIdx.x;
  if (blk >= 8192 && blk < 16384) {
    int x = blk - 8192;
    int n = ((x & 7) << 10) | (x >> 3);   // frame f -> XCD f
    int b = n >> 10;
    int l = t & 15;
    int s = t >> 4;
    const __half* f0 = F0 + (size_t)b * 1024 * 256 + l * 16;
    const __half* f1 = F1 + (size_t)b * 4096 * 256 + l * 16;
    int j1 = poff[n + 1];
    __half2 z = __float2half2_rn(0.f);
    __half2 a0[8], a1[8];
#pragma unroll
    for (int i = 0; i < 8; ++i) { a0[i] = z; a1[i] = z; }
    for (int j = poff[n] + s; j < j1; j += 16) {
      int p = psorted[j];
      int h = (p >> 8) & 255, w = p & 255;
      taps16<32>(f0, h, w, a0);
      taps16<64>(f1, h, w, a1);
    }
    uint (*red)[256][9] = (uint(*)[256][9])smem;
#pragma unroll
    for (int k = 0; k < 8; ++k) { red[0][t][k] = h2u(a0[k]); red[1][t][k] = h2u(a1[k]); }
    __syncthreads();
    if (t < 128) {
      int l2 = t >> 3, k = t & 7;
      float r = rc[n];
      float2 s0 = make_float2(0.f, 0.f), s1 = s0;
#pragma unroll
      for (int ss = 0; ss < 16; ++ss) {
        float2 v0 = __half22float2(uh2(red[0][ss * 16 + l2][k]));
        float2 v1 = __half22float2(uh2(red[1][ss * 16 + l2][k]));
        s0.x += v0.x; s0.y += v0.y;
        s1.x += v1.x; s1.y += v1.y;
      }
      int c = l2 * 16 + k * 2;
      *(uint*)&p0out[(size_t)n * 256 + c] = packh2(s0.x * r, s0.y * r);
      *(float2*)&p1out[(size_t)n * 256 + c] = make_float2(s1.x * r, s1.y * r);
    }
  } else {
    int x, c0;
    if (blk < 8192) { x = blk; c0 = 0; }
    else            { x = blk - 16384; c0 = 128; }
    int n = ((x & 7) << 10) | (x >> 3);
    int b = n >> 10;
    int l = t & 7;
    int s = t >> 3;
    const __half* fb = F2 + (size_t)b * 16384 * 256 + c0 + l * 16;
    int j1 = poff[n + 1];
    __half2 z = __float2half2_rn(0.f);
    __half2 acc[8];
#pragma unroll
    for (int i = 0; i < 8; ++i) acc[i] = z;
    for (int j = poff[n] + s; j < j1; j += 32) {
      int p = psorted[j];
      int h = (p >> 8) & 255, w = p & 255;
      taps16<128>(fb, h, w, acc);
    }
    uint (*red)[9] = (uint(*)[9])smem;
#pragma unroll
    for (int k = 0; k < 8; ++k) red[t][k] = h2u(acc[k]);
    __syncthreads();
    if (t < 64) {
      int l2 = t >> 3, k = t & 7;
      float r = rc[n];
      float2 sm = make_float2(0.f, 0.f);
#pragma unroll
      for (int ss = 0; ss < 32; ++ss) {
        float2 v = __half22float2(uh2(red[ss * 8 + l2][k]));
        sm.x += v.x; sm.y += v.y;
      }
      int c = c0 + l2 * 16 + k * 2;
      *(float2*)&p2out[(size_t)n * 256 + c] = make_float2(sm.x * r, sm.y * r);
    }
  }
}

// ---------------- CSR edge aggregation + bias + relu; h is f16, 2 nodes/block ----------------
__global__ __launch_bounds__(256) void agg_kernel(const __half* __restrict__ h, const float* __restrict__ bias,
                                                  const int* __restrict__ eoff,
                                                  const uint2* __restrict__ evw,
                                                  float* __restrict__ xout) {
  int n = blockIdx.x * 2 + (threadIdx.x >> 7);
  int c2 = threadIdx.x & 127;
  int e0 = eoff[n], e1 = eoff[n + 1];
  float a0 = 0.f, a1 = 0.f;
  for (int j = e0; j < e1; ++j) {
    uint2 ev = evw[j];
    float wv = __uint_as_float(ev.y);
    uint hv = *(const uint*)&h[((size_t)ev.x << 8) + c2 * 2];
    float2 f = __half22float2(uh2(hv));
    a0 += wv * f.x;
    a1 += wv * f.y;
  }
  float v0 = a0 + bias[2 * c2];
  float v1 = a1 + bias[2 * c2 + 1];
  *(float2*)&xout[((size_t)n << 8) + 2 * c2] =
      make_float2(v0 > 0.f ? v0 : 0.f, v1 > 0.f ? v1 : 0.f);
}

// ---------------- final agg + in-block score: s[n] = relu(agg+b) . lw  ----------------
__global__ __launch_bounds__(256) void agg_score_kernel(const __half* __restrict__ h,
                                                        const float* __restrict__ bias,
                                                        const int* __restrict__ eoff,
                                                        const uint2* __restrict__ evw,
                                                        const float* __restrict__ lw,
                                                        float* __restrict__ s) {
  int t = threadIdx.x;
  int n = blockIdx.x * 2 + (t >> 7);
  int c2 = t & 127;
  int e0 = eoff[n], e1 = eoff[n + 1];
  float a0 = 0.f, a1 = 0.f;
  for (int j = e0; j < e1; ++j) {
    uint2 ev = evw[j];
    float wv = __uint_as_float(ev.y);
    uint hv = *(const uint*)&h[((size_t)ev.x << 8) + c2 * 2];
    float2 f = __half22float2(uh2(hv));
    a0 += wv * f.x;
    a1 += wv * f.y;
  }
  float v0 = a0 + bias[2 * c2];
  float v1 = a1 + bias[2 * c2 + 1];
  v0 = v0 > 0.f ? v0 : 0.f;
  v1 = v1 > 0.f ? v1 : 0.f;
  float p = v0 * lw[2 * c2] + v1 * lw[2 * c2 + 1];
#pragma unroll
  for (int off = 32; off > 0; off >>= 1) p += __shfl_down(p, off, 64);
  __shared__ float ws[4];
  if ((t & 63) == 0) ws[t >> 6] = p;
  __syncthreads();
  if (t == 0)   s[n] = ws[0] + ws[1];
  if (t == 128) s[n] = ws[2] + ws[3];
}

// ---------------- GEMM with fused mix: out = (0.5*(X+P)) @ W, K=N=256, f16 out ----------------
__global__ __launch_bounds__(256) void gemm_mix_n256(const float* __restrict__ X, const float* __restrict__ Pl,
                                                     const float* __restrict__ W, __half* __restrict__ out) {
  const int t = threadIdx.x;
  const int r0 = blockIdx.x * 16;
  const int cw = (t & 63) * 4;
  const int rg = (t >> 6) * 4;
  __shared__ float Xl[16][68];
  float4 acc[4];
#pragma unroll
  for (int i = 0; i < 4; ++i) acc[i] = make_float4(0.f, 0.f, 0.f, 0.f);
  for (int k0 = 0; k0 < 256; k0 += 64) {
#pragma unroll
    for (int l = 0; l < 4; ++l) {
      int idx = t + 256 * l;
      int r = idx >> 6, k = idx & 63;
      size_t a = (size_t)(r0 + r) * 256 + k0 + k;
      Xl[r][k] = 0.5f * (X[a] + Pl[a]);
    }
    __syncthreads();
#pragma unroll
    for (int k4 = 0; k4 < 64; k4 += 4) {
      float4 a[4];
#pragma unroll
      for (int i = 0; i < 4; ++i) a[i] = *(const float4*)&Xl[rg + i][k4];
#pragma unroll
      for (int kk = 0; kk < 4; ++kk) {
        float4 w = *(const float4*)&W[(size_t)(k0 + k4 + kk) * 256 + cw];
#pragma unroll
        for (int i = 0; i < 4; ++i) {
          float av = ((const float*)&a[i])[kk];
          acc[i].x += av * w.x;
          acc[i].y += av * w.y;
          acc[i].z += av * w.z;
          acc[i].w += av * w.w;
        }
      }
    }
    __syncthreads();
  }
#pragma unroll
  for (int i = 0; i < 4; ++i) {
    uint2 pk = make_uint2(packh2(acc[i].x, acc[i].y), packh2(acc[i].z, acc[i].w));
    *(uint2*)&out[(size_t)(r0 + rg + i) * 256 + cw] = pk;
  }
}

// ---------------- final sigmoids ----------------
__global__ __launch_bounds__(256) void out_kernel(const float* __restrict__ s, const int* __restrict__ src,
                                                  const int* __restrict__ dst, const int* __restrict__ negs,
                                                  float* __restrict__ outp) {
  int e = blockIdx.x * 256 + threadIdx.x;
  if (e >= EE) return;
  float ss = s[src[e]];
  float a = ss - s[negs[e]];
  float b = ss - s[dst[e]];
  outp[e] = 1.0f / (1.0f + expf(-a));         // dan
  outp[EE + e] = 1.0f / (1.0f + expf(-b));    // dap
}

extern "C" void kernel_launch(void* const* d_in, const int* in_sizes, int n_in,
                              void* d_out, int out_size, void* d_ws, size_t ws_size,
                              hipStream_t stream) {
  const int*   labels = (const int*)d_in[0];
  const float* skip0  = (const float*)d_in[1];
  const float* skip1  = (const float*)d_in[2];
  const float* skip2  = (const float*)d_in[3];
  const int*   edges  = (const int*)d_in[4];
  const int*   negs   = (const int*)d_in[5];
  const float* W0     = (const float*)d_in[6];
  const float* b0     = (const float*)d_in[7];
  const float* W1     = (const float*)d_in[8];
  const float* b1     = (const float*)d_in[9];
  const float* W2     = (const float*)d_in[10];
  const float* b2     = (const float*)d_in[11];
  const float* lw     = (const float*)d_in[12];
  const int* esrc = edges;
  const int* edst = edges + EE;
  float* outp = (float*)d_out;

  // ---- workspace bump allocator (256B aligned) ----
  size_t o = 0;
  char* base = (char*)d_ws;
  auto alloc = [&](size_t bytes) -> void* {
    void* p = base + o;
    o += (bytes + 255) & ~(size_t)255;
    return p;
  };
  // zeroed block (contiguous at front)
  u64* packed  = (u64*)alloc(NNODE * 8);
  int* cnt_e   = (int*)alloc(NNODE * 4);
  int* ecur    = (int*)alloc(NNODE * 4);
  int* pcur    = (int*)alloc(NNODE * 4);
  size_t zbytes = o;
  // non-zeroed
  float*  rcnt    = (float*)alloc(NNODE * 4);
  float*  pch     = (float*)alloc(NNODE * 4);
  float*  pcw     = (float*)alloc(NNODE * 4);
  int*    poff    = (int*)alloc((NNODE + 1) * 4);
  int*    eoff    = (int*)alloc((NNODE + 1) * 4);
  uint2*  evw     = (uint2*)alloc((size_t)EE * 8);
  int*    psorted = (int*)alloc(NPIX * 4);
  int*    segb    = (int*)alloc(NPIX * 4);
  float*  bufA    = (float*)alloc((size_t)NNODE * CH * 4);
  float*  bufB    = (float*)alloc((size_t)NNODE * CH * 4);
  float*  p1buf   = (float*)alloc((size_t)NNODE * CH * 4);
  float*  p2buf   = (float*)alloc((size_t)NNODE * CH * 4);
  __half* h0b     = (__half*)alloc((size_t)NNODE * CH * 2);       // 4 MB
  __half* h1b     = (__half*)alloc((size_t)NNODE * CH * 2);       // 4 MB (reused for h2)
  __half* F0b     = (__half*)alloc((size_t)BB * 1024 * CH * 2);   // 4 MB
  __half* F1t     = (__half*)alloc((size_t)BB * 4096 * CH * 2);   // 16.8 MB
  __half* F2t     = (__half*)alloc((size_t)BB * 16384 * CH * 2);  // 67 MB
  float*  sbuf    = (float*)alloc(NNODE * 4);
  (void)ws_size; (void)n_in; (void)in_sizes; (void)out_size;

  // 1. zero accumulators
  zero_kernel<<<64, 256, 0, stream>>>((int4*)d_ws, (int)(zbytes / 16));
  // 2. cnt2: seg-count + edge-count atomics
  cnt2_kernel<<<2048 + 512, 256, 0, stream>>>(labels, edst, segb, packed, cnt_e);
  // 3. FUSED-B: dual scan || rcnt/centroids
  fusedB_kernel<<<10, 1024, 0, stream>>>(packed, cnt_e, poff, eoff, rcnt, pch, pcw);
  // 4. T2K: skip2+skip1 transposes, full-channel tiles -> 32 KB contiguous writes/block
  t2k_kernel<<<2560, 256, 0, stream>>>(skip2, F2t, skip1, F1t);
  // 5. FUSED-S: scatter2 || skip0@W0
  fusedS_kernel<<<3072, 256, 0, stream>>>(skip0, W0, F0b, segb, poff, pcur, psorted,
                                          esrc, edst, pch, pcw, eoff, ecur, evw, outp);
  // 6. FUSED-C: gather2(half0) -> gather01 -> gather2(half1)
  fusedC_kernel<<<24576, 256, 0, stream>>>(F0b, F1t, F2t, poff, psorted, rcnt,
                                           h0b, p1buf, p2buf);
  // 7. layer0 aggregate (h0 f16) -> x1
  agg_kernel<<<NNODE / 2, 256, 0, stream>>>(h0b, b0, eoff, evw, bufB);
  // 8-9. layer1 (mix fused into GEMM, f16 h out)
  gemm_mix_n256<<<NNODE / 16, 256, 0, stream>>>(bufB, p1buf, W1, h1b);
  agg_kernel<<<NNODE / 2, 256, 0, stream>>>(h1b, b1, eoff, evw, bufA);
  // 10. layer2 GEMM
  gemm_mix_n256<<<NNODE / 16, 256, 0, stream>>>(bufA, p2buf, W2, h1b);
  // 11. final aggregate + in-block score
  agg_score_kernel<<<NNODE / 2, 256, 0, stream>>>(h1b, b2, eoff, evw, lw, sbuf);
  // 12. dan / dap
  out_kernel<<<EE / 256, 256, 0, stream>>>(sbuf, esrc, edst, negs, outp);
}

// Round 9
// 691.104 us; speedup vs baseline: 1.0404x; 1.0404x over previous
//
#include <hip/hip_runtime.h>
#include <hip/hip_fp16.h>
#include <cstdint>
#include <cstddef>

#define BB 8
#define NSPX 1024
#define NNODE 8192      // BB*NSPX
#define EE 131072
#define NPIX 524288     // BB*256*256
#define CH 256

typedef unsigned int uint;
typedef unsigned long long u64;

__device__ __forceinline__ uint packh2(float a, float b) {
  __half2 h = __float22half2_rn(make_float2(a, b));
  return *reinterpret_cast<uint*>(&h);
}
__device__ __forceinline__ __half2 uh2(uint u) { return *reinterpret_cast<__half2*>(&u); }
__device__ __forceinline__ uint h2u(__half2 h) { return *reinterpret_cast<uint*>(&h); }

// ---------------- zero workspace accumulators ----------------
__global__ __launch_bounds__(256) void zero_kernel(int4* p, int n4) {
  int i = blockIdx.x * 256 + threadIdx.x;
  int stride = gridDim.x * 256;
  int4 z = make_int4(0, 0, 0, 0);
  for (; i < n4; i += stride) p[i] = z;
}

// ---------------- device: transpose [B,256,P] -> [B,P,256] f16, FULL 256ch x 64px tile ----
__device__ __forceinline__ void dev_transpose_full(const float* __restrict__ src, __half* __restrict__ dst,
                                                   int P, int b, int p0, int t,
                                                   uint (*tile)[33]) {
  int l16 = t & 15, r16 = t >> 4;
#pragma unroll
  for (int pass = 0; pass < 16; ++pass) {
    int c = pass * 16 + r16;
    float4 v = *(const float4*)&src[((size_t)b * 256 + c) * P + p0 + l16 * 4];
    tile[c][l16 * 2]     = packh2(v.x, v.y);   // pixels (p, p+1) of channel c
    tile[c][l16 * 2 + 1] = packh2(v.z, v.w);
  }
  __syncthreads();
  int q = t & 31, r8 = t >> 5;
#pragma unroll
  for (int pass = 0; pass < 8; ++pass) {
    int p = pass * 8 + r8;
    int ph = p >> 1;
    int odd = p & 1;
    uint r[4];
#pragma unroll
    for (int j = 0; j < 4; ++j) {
      uint ua = tile[q * 8 + 2 * j][ph];       // channels 8q+2j, pixels (2ph, 2ph+1)
      uint ub = tile[q * 8 + 2 * j + 1][ph];   // channel 8q+2j+1
      r[j] = odd ? ((ua >> 16) | (ub & 0xFFFF0000u))
                 : ((ua & 0xFFFFu) | (ub << 16));
    }
    *(uint4*)&dst[((size_t)b * P + p0 + p) * 256 + q * 8] = make_uint4(r[0], r[1], r[2], r[3]);
  }
}

// ---------------- device: skip0 fold out[b][m][n] = sum_k skip0[b][k][m]*W0[k][n], f16 out ----
__device__ __forceinline__ void dev_gemm_kmaj(const float* __restrict__ A, const float* __restrict__ W,
                                              __half* __restrict__ out, int idx, int t,
                                              float (*As)[36]) {
  int b = idx >> 6;
  int m0 = (idx & 31) * 32;
  int n0 = ((idx >> 5) & 1) * 128;
  int ct = t & 31;
  int rm = t >> 5;
  int l8 = t & 7, kr = t >> 3;
  const float* Ab = A + (size_t)b * 512 * 1024;
  float4 acc[4];
#pragma unroll
  for (int i = 0; i < 4; ++i) acc[i] = make_float4(0.f, 0.f, 0.f, 0.f);
  for (int k0 = 0; k0 < 512; k0 += 64) {
#pragma unroll
    for (int pass = 0; pass < 2; ++pass) {
      int k = kr + pass * 32;
      float4 v = *(const float4*)&Ab[(size_t)(k0 + k) * 1024 + m0 + l8 * 4];
      *(float4*)&As[k][l8 * 4] = v;
    }
    __syncthreads();
#pragma unroll 8
    for (int k = 0; k < 64; ++k) {
      float4 a = *(const float4*)&As[k][rm * 4];
      float4 wv = *(const float4*)&W[(size_t)(k0 + k) * 256 + n0 + ct * 4];
      acc[0].x += a.x * wv.x; acc[0].y += a.x * wv.y; acc[0].z += a.x * wv.z; acc[0].w += a.x * wv.w;
      acc[1].x += a.y * wv.x; acc[1].y += a.y * wv.y; acc[1].z += a.y * wv.z; acc[1].w += a.y * wv.w;
      acc[2].x += a.z * wv.x; acc[2].y += a.z * wv.y; acc[2].z += a.z * wv.z; acc[2].w += a.z * wv.w;
      acc[3].x += a.w * wv.x; acc[3].y += a.w * wv.y; acc[3].z += a.w * wv.z; acc[3].w += a.w * wv.w;
    }
    __syncthreads();
  }
#pragma unroll
  for (int i = 0; i < 4; ++i) {
    int m = m0 + rm * 4 + i;
    uint2 pk = make_uint2(packh2(acc[i].x, acc[i].y), packh2(acc[i].z, acc[i].w));
    *(uint2*)&out[((size_t)b * 1024 + m) * 256 + n0 + ct * 4] = pk;
  }
}

// ---------------- HEAD: t2k (2560 blk, first -> stream starts at t=0) || cnt2 (2560) || gemm (512) ----
// All three depend only on kernel inputs. cnt2's atomics and the gemm's VALU ride under the
// transpose's HBM stream (t2k alone: 31% occupancy, 14% VALU). Removes 2 launch boundaries
// and ~55 us of serial exposure vs R8's {cnt2, t2k, fusedS} split.
__global__ __launch_bounds__(256) void head_kernel(const float* __restrict__ skip2, __half* __restrict__ F2t,
                                                   const float* __restrict__ skip1, __half* __restrict__ F1t,
                                                   const int* __restrict__ labels,
                                                   const int* __restrict__ edst,
                                                   int* __restrict__ segb,
                                                   u64* __restrict__ packed,
                                                   int* __restrict__ cnt_e,
                                                   const float* __restrict__ skip0,
                                                   const float* __restrict__ W0,
                                                   __half* __restrict__ F0b) {
  __shared__ __align__(16) char smem[33792];   // max(tile 256x33 u32 = 33792, As 64x36 f32 = 9216)
  int blk = blockIdx.x;
  int t = threadIdx.x;
  if (blk < 2048) {
    // skip2 transpose
    int p0 = (blk & 255) * 64;
    int b = blk >> 8;
    dev_transpose_full(skip2, F2t, 16384, b, p0, t, (uint(*)[33])smem);
  } else if (blk < 2560) {
    // skip1 transpose
    int i2 = blk - 2048;               // 0..511
    int p0 = (i2 & 63) * 64;
    int b = i2 >> 6;
    dev_transpose_full(skip1, F1t, 4096, b, p0, t, (uint(*)[33])smem);
  } else if (blk < 4608) {
    // cnt2 pixel: seg ids + packed(cnt,h,w) atomics
    int p = (blk - 2560) * 256 + t;
    int b = p >> 16;
    int h = (p >> 8) & 255;
    int w = p & 255;
    int seg = labels[p] + (b << 10);
    segb[p] = seg;
    u64 enc = (1ULL << 48) | ((u64)h << 24) | (u64)w;
    atomicAdd(&packed[seg], enc);
  } else if (blk < 5120) {
    // cnt2 edge: dst counting
    int e = (blk - 4608) * 256 + t;
    atomicAdd(&cnt_e[edst[e]], 1);
  } else {
    // skip0 @ W0
    dev_gemm_kmaj(skip0, W0, F0b, blk - 5120, t, (float(*)[36])smem);
  }
}

// ---------------- FUSED-B: dual scan (blocks 0-1) || rcnt/centroids (blocks 2-9) ----------------
__global__ __launch_bounds__(1024) void fusedB_kernel(const u64* __restrict__ packed,
                                                      const int* __restrict__ cnt_e,
                                                      int* __restrict__ poff, int* __restrict__ eoff,
                                                      float* __restrict__ rcnt,
                                                      float* __restrict__ pch, float* __restrict__ pcw) {
  int blk = blockIdx.x;
  int t = threadIdx.x;
  if (blk < 2) {
    __shared__ int ps[1024];
    int which = blk;
    int* coff = which ? eoff : poff;
    int base = t * 8;
    int v[8];
    int sum = 0;
#pragma unroll
    for (int i = 0; i < 8; ++i) {
      int x = which ? cnt_e[base + i] : (int)(packed[base + i] >> 48);
      v[i] = sum;
      sum += x;
    }
    ps[t] = sum;
    __syncthreads();
    for (int off = 1; off < 1024; off <<= 1) {
      int x = (t >= off) ? ps[t - off] : 0;
      __syncthreads();
      ps[t] += x;
      __syncthreads();
    }
    int prev = (t == 0) ? 0 : ps[t - 1];
#pragma unroll
    for (int i = 0; i < 8; ++i) coff[base + i] = prev + v[i];
    if (t == 1023) coff[8192] = ps[1023];
  } else {
    int n = (blk - 2) * 1024 + t;
    u64 v = packed[n];
    int c = (int)(v >> 48);
    int sh = (int)((v >> 24) & 0xFFFFFF);
    int sw = (int)(v & 0xFFFFFF);
    float r = 1.0f / (float)(c > 1 ? c : 1);
    rcnt[n] = r;
    pch[n] = (float)sh * r * (1.0f / 255.0f);
    pcw[n] = (float)sw * r * (1.0f / 255.0f);
  }
}

// ---------------- scatter2: pixel CSR scatter | edge attr + CSR scatter of (src,ew) ----------------
__global__ __launch_bounds__(256) void scatter2_kernel(const int* __restrict__ segb,
                                                       const int* __restrict__ poff,
                                                       int* __restrict__ pcur,
                                                       int* __restrict__ psorted,
                                                       const int* __restrict__ esrc,
                                                       const int* __restrict__ edst,
                                                       const float* __restrict__ pch,
                                                       const float* __restrict__ pcw,
                                                       const int* __restrict__ eoff,
                                                       int* __restrict__ ecur,
                                                       uint2* __restrict__ evw,
                                                       float* __restrict__ outp) {
  int blk = blockIdx.x;
  int t = threadIdx.x;
  if (blk < 2048) {
    int p = blk * 256 + t;
    int sg = segb[p];
    int pos = poff[sg] + atomicAdd(&pcur[sg], 1);
    psorted[pos] = p;
  } else {
    int e = (blk - 2048) * 256 + t;
    int s1 = esrc[e], d1 = edst[e];
    float dh = pch[s1] - pch[d1];
    float dw = pcw[s1] - pcw[d1];
    float ea = expf(-(dh * dh + dw * dw) * 20.0f);
    outp[2 * EE + e] = ea;
    int pos = eoff[d1] + atomicAdd(&ecur[d1], 1);
    evw[pos] = make_uint2((uint)s1, __float_as_uint(ea));
  }
}

// ---------------- gather pooling: packed-f16 tap accumulate (16 ch / lane) ----------------
__device__ __forceinline__ void tap16(const __half* __restrict__ tp, float wt, __half2* acc) {
  uint4 qa = *(const uint4*)tp;
  uint4 qb = *(const uint4*)(tp + 8);
  __half2 W = __float2half2_rn(wt);
  acc[0] = __hfma2(W, uh2(qa.x), acc[0]);
  acc[1] = __hfma2(W, uh2(qa.y), acc[1]);
  acc[2] = __hfma2(W, uh2(qa.z), acc[2]);
  acc[3] = __hfma2(W, uh2(qa.w), acc[3]);
  acc[4] = __hfma2(W, uh2(qb.x), acc[4]);
  acc[5] = __hfma2(W, uh2(qb.y), acc[5]);
  acc[6] = __hfma2(W, uh2(qb.z), acc[6]);
  acc[7] = __hfma2(W, uh2(qb.w), acc[7]);
}

template <int HS>
__device__ __forceinline__ void taps16(const __half* __restrict__ fb, int h, int w, __half2* acc) {
  const float fh = (float)(HS - 1) / 255.0f;
  float ph = h * fh, pw = w * fh;
  int i0 = (int)ph, j0 = (int)pw;
  float th = ph - (float)i0, tw = pw - (float)j0;
  int i1 = min(i0 + 1, HS - 1), jj1 = min(j0 + 1, HS - 1);
  float w11 = th * tw, w10 = th - w11, w01 = tw - w11, w00 = 1.f - th - tw + w11;
  tap16(fb + (i0 * HS + j0) * 256, w00, acc);
  tap16(fb + (i0 * HS + jj1) * 256, w01, acc);
  tap16(fb + (i1 * HS + j0) * 256, w10, acc);
  tap16(fb + (i1 * HS + jj1) * 256, w11, acc);
}

// ---------------- FUSED-C: gather2(half0) -> gather01 -> gather2(half1) ----------------
__global__ __launch_bounds__(256) void fusedC_kernel(const __half* __restrict__ F0,
                                                     const __half* __restrict__ F1,
                                                     const __half* __restrict__ F2,
                                                     const int* __restrict__ poff,
                                                     const int* __restrict__ psorted,
                                                     const float* __restrict__ rc,
                                                     __half* __restrict__ p0out,
                                                     float* __restrict__ p1out,
                                                     float* __restrict__ p2out) {
  __shared__ __align__(16) char smem[18432];
  int blk = blockIdx.x;
  int t = threadIdx.x;
  if (blk >= 8192 && blk < 16384) {
    int x = blk - 8192;
    int n = ((x & 7) << 10) | (x >> 3);   // frame f -> XCD f
    int b = n >> 10;
    int l = t & 15;
    int s = t >> 4;
    const __half* f0 = F0 + (size_t)b * 1024 * 256 + l * 16;
    const __half* f1 = F1 + (size_t)b * 4096 * 256 + l * 16;
    int j1 = poff[n + 1];
    __half2 z = __float2half2_rn(0.f);
    __half2 a0[8], a1[8];
#pragma unroll
    for (int i = 0; i < 8; ++i) { a0[i] = z; a1[i] = z; }
    for (int j = poff[n] + s; j < j1; j += 16) {
      int p = psorted[j];
      int h = (p >> 8) & 255, w = p & 255;
      taps16<32>(f0, h, w, a0);
      taps16<64>(f1, h, w, a1);
    }
    uint (*red)[256][9] = (uint(*)[256][9])smem;
#pragma unroll
    for (int k = 0; k < 8; ++k) { red[0][t][k] = h2u(a0[k]); red[1][t][k] = h2u(a1[k]); }
    __syncthreads();
    if (t < 128) {
      int l2 = t >> 3, k = t & 7;
      float r = rc[n];
      float2 s0 = make_float2(0.f, 0.f), s1 = s0;
#pragma unroll
      for (int ss = 0; ss < 16; ++ss) {
        float2 v0 = __half22float2(uh2(red[0][ss * 16 + l2][k]));
        float2 v1 = __half22float2(uh2(red[1][ss * 16 + l2][k]));
        s0.x += v0.x; s0.y += v0.y;
        s1.x += v1.x; s1.y += v1.y;
      }
      int c = l2 * 16 + k * 2;
      *(uint*)&p0out[(size_t)n * 256 + c] = packh2(s0.x * r, s0.y * r);
      *(float2*)&p1out[(size_t)n * 256 + c] = make_float2(s1.x * r, s1.y * r);
    }
  } else {
    int x, c0;
    if (blk < 8192) { x = blk; c0 = 0; }
    else            { x = blk - 16384; c0 = 128; }
    int n = ((x & 7) << 10) | (x >> 3);
    int b = n >> 10;
    int l = t & 7;
    int s = t >> 3;
    const __half* fb = F2 + (size_t)b * 16384 * 256 + c0 + l * 16;
    int j1 = poff[n + 1];
    __half2 z = __float2half2_rn(0.f);
    __half2 acc[8];
#pragma unroll
    for (int i = 0; i < 8; ++i) acc[i] = z;
    for (int j = poff[n] + s; j < j1; j += 32) {
      int p = psorted[j];
      int h = (p >> 8) & 255, w = p & 255;
      taps16<128>(fb, h, w, acc);
    }
    uint (*red)[9] = (uint(*)[9])smem;
#pragma unroll
    for (int k = 0; k < 8; ++k) red[t][k] = h2u(acc[k]);
    __syncthreads();
    if (t < 64) {
      int l2 = t >> 3, k = t & 7;
      float r = rc[n];
      float2 sm = make_float2(0.f, 0.f);
#pragma unroll
      for (int ss = 0; ss < 32; ++ss) {
        float2 v = __half22float2(uh2(red[ss * 8 + l2][k]));
        sm.x += v.x; sm.y += v.y;
      }
      int c = c0 + l2 * 16 + k * 2;
      *(float2*)&p2out[(size_t)n * 256 + c] = make_float2(sm.x * r, sm.y * r);
    }
  }
}

// ---------------- CSR edge aggregation + bias + relu; h is f16, 2 nodes/block ----------------
__global__ __launch_bounds__(256) void agg_kernel(const __half* __restrict__ h, const float* __restrict__ bias,
                                                  const int* __restrict__ eoff,
                                                  const uint2* __restrict__ evw,
                                                  float* __restrict__ xout) {
  int n = blockIdx.x * 2 + (threadIdx.x >> 7);
  int c2 = threadIdx.x & 127;
  int e0 = eoff[n], e1 = eoff[n + 1];
  float a0 = 0.f, a1 = 0.f;
  for (int j = e0; j < e1; ++j) {
    uint2 ev = evw[j];
    float wv = __uint_as_float(ev.y);
    uint hv = *(const uint*)&h[((size_t)ev.x << 8) + c2 * 2];
    float2 f = __half22float2(uh2(hv));
    a0 += wv * f.x;
    a1 += wv * f.y;
  }
  float v0 = a0 + bias[2 * c2];
  float v1 = a1 + bias[2 * c2 + 1];
  *(float2*)&xout[((size_t)n << 8) + 2 * c2] =
      make_float2(v0 > 0.f ? v0 : 0.f, v1 > 0.f ? v1 : 0.f);
}

// ---------------- final agg + in-block score: s[n] = relu(agg+b) . lw  ----------------
__global__ __launch_bounds__(256) void agg_score_kernel(const __half* __restrict__ h,
                                                        const float* __restrict__ bias,
                                                        const int* __restrict__ eoff,
                                                        const uint2* __restrict__ evw,
                                                        const float* __restrict__ lw,
                                                        float* __restrict__ s) {
  int t = threadIdx.x;
  int n = blockIdx.x * 2 + (t >> 7);
  int c2 = t & 127;
  int e0 = eoff[n], e1 = eoff[n + 1];
  float a0 = 0.f, a1 = 0.f;
  for (int j = e0; j < e1; ++j) {
    uint2 ev = evw[j];
    float wv = __uint_as_float(ev.y);
    uint hv = *(const uint*)&h[((size_t)ev.x << 8) + c2 * 2];
    float2 f = __half22float2(uh2(hv));
    a0 += wv * f.x;
    a1 += wv * f.y;
  }
  float v0 = a0 + bias[2 * c2];
  float v1 = a1 + bias[2 * c2 + 1];
  v0 = v0 > 0.f ? v0 : 0.f;
  v1 = v1 > 0.f ? v1 : 0.f;
  float p = v0 * lw[2 * c2] + v1 * lw[2 * c2 + 1];
#pragma unroll
  for (int off = 32; off > 0; off >>= 1) p += __shfl_down(p, off, 64);
  __shared__ float ws[4];
  if ((t & 63) == 0) ws[t >> 6] = p;
  __syncthreads();
  if (t == 0)   s[n] = ws[0] + ws[1];
  if (t == 128) s[n] = ws[2] + ws[3];
}

// ---------------- GEMM with fused mix: out = (0.5*(X+P)) @ W, K=N=256, f16 out ----------------
__global__ __launch_bounds__(256) void gemm_mix_n256(const float* __restrict__ X, const float* __restrict__ Pl,
                                                     const float* __restrict__ W, __half* __restrict__ out) {
  const int t = threadIdx.x;
  const int r0 = blockIdx.x * 16;
  const int cw = (t & 63) * 4;
  const int rg = (t >> 6) * 4;
  __shared__ float Xl[16][68];
  float4 acc[4];
#pragma unroll
  for (int i = 0; i < 4; ++i) acc[i] = make_float4(0.f, 0.f, 0.f, 0.f);
  for (int k0 = 0; k0 < 256; k0 += 64) {
#pragma unroll
    for (int l = 0; l < 4; ++l) {
      int idx = t + 256 * l;
      int r = idx >> 6, k = idx & 63;
      size_t a = (size_t)(r0 + r) * 256 + k0 + k;
      Xl[r][k] = 0.5f * (X[a] + Pl[a]);
    }
    __syncthreads();
#pragma unroll
    for (int k4 = 0; k4 < 64; k4 += 4) {
      float4 a[4];
#pragma unroll
      for (int i = 0; i < 4; ++i) a[i] = *(const float4*)&Xl[rg + i][k4];
#pragma unroll
      for (int kk = 0; kk < 4; ++kk) {
        float4 w = *(const float4*)&W[(size_t)(k0 + k4 + kk) * 256 + cw];
#pragma unroll
        for (int i = 0; i < 4; ++i) {
          float av = ((const float*)&a[i])[kk];
          acc[i].x += av * w.x;
          acc[i].y += av * w.y;
          acc[i].z += av * w.z;
          acc[i].w += av * w.w;
        }
      }
    }
    __syncthreads();
  }
#pragma unroll
  for (int i = 0; i < 4; ++i) {
    uint2 pk = make_uint2(packh2(acc[i].x, acc[i].y), packh2(acc[i].z, acc[i].w));
    *(uint2*)&out[(size_t)(r0 + rg + i) * 256 + cw] = pk;
  }
}

// ---------------- final sigmoids ----------------
__global__ __launch_bounds__(256) void out_kernel(const float* __restrict__ s, const int* __restrict__ src,
                                                  const int* __restrict__ dst, const int* __restrict__ negs,
                                                  float* __restrict__ outp) {
  int e = blockIdx.x * 256 + threadIdx.x;
  if (e >= EE) return;
  float ss = s[src[e]];
  float a = ss - s[negs[e]];
  float b = ss - s[dst[e]];
  outp[e] = 1.0f / (1.0f + expf(-a));         // dan
  outp[EE + e] = 1.0f / (1.0f + expf(-b));    // dap
}

extern "C" void kernel_launch(void* const* d_in, const int* in_sizes, int n_in,
                              void* d_out, int out_size, void* d_ws, size_t ws_size,
                              hipStream_t stream) {
  const int*   labels = (const int*)d_in[0];
  const float* skip0  = (const float*)d_in[1];
  const float* skip1  = (const float*)d_in[2];
  const float* skip2  = (const float*)d_in[3];
  const int*   edges  = (const int*)d_in[4];
  const int*   negs   = (const int*)d_in[5];
  const float* W0     = (const float*)d_in[6];
  const float* b0     = (const float*)d_in[7];
  const float* W1     = (const float*)d_in[8];
  const float* b1     = (const float*)d_in[9];
  const float* W2     = (const float*)d_in[10];
  const float* b2     = (const float*)d_in[11];
  const float* lw     = (const float*)d_in[12];
  const int* esrc = edges;
  const int* edst = edges + EE;
  float* outp = (float*)d_out;

  // ---- workspace bump allocator (256B aligned) ----
  size_t o = 0;
  char* base = (char*)d_ws;
  auto alloc = [&](size_t bytes) -> void* {
    void* p = base + o;
    o += (bytes + 255) & ~(size_t)255;
    return p;
  };
  // zeroed block (contiguous at front)
  u64* packed  = (u64*)alloc(NNODE * 8);
  int* cnt_e   = (int*)alloc(NNODE * 4);
  int* ecur    = (int*)alloc(NNODE * 4);
  int* pcur    = (int*)alloc(NNODE * 4);
  size_t zbytes = o;
  // non-zeroed
  float*  rcnt    = (float*)alloc(NNODE * 4);
  float*  pch     = (float*)alloc(NNODE * 4);
  float*  pcw     = (float*)alloc(NNODE * 4);
  int*    poff    = (int*)alloc((NNODE + 1) * 4);
  int*    eoff    = (int*)alloc((NNODE + 1) * 4);
  uint2*  evw     = (uint2*)alloc((size_t)EE * 8);
  int*    psorted = (int*)alloc(NPIX * 4);
  int*    segb    = (int*)alloc(NPIX * 4);
  float*  bufA    = (float*)alloc((size_t)NNODE * CH * 4);
  float*  bufB    = (float*)alloc((size_t)NNODE * CH * 4);
  float*  p1buf   = (float*)alloc((size_t)NNODE * CH * 4);
  float*  p2buf   = (float*)alloc((size_t)NNODE * CH * 4);
  __half* h0b     = (__half*)alloc((size_t)NNODE * CH * 2);       // 4 MB
  __half* h1b     = (__half*)alloc((size_t)NNODE * CH * 2);       // 4 MB (reused for h2)
  __half* F0b     = (__half*)alloc((size_t)BB * 1024 * CH * 2);   // 4 MB
  __half* F1t     = (__half*)alloc((size_t)BB * 4096 * CH * 2);   // 16.8 MB
  __half* F2t     = (__half*)alloc((size_t)BB * 16384 * CH * 2);  // 67 MB
  float*  sbuf    = (float*)alloc(NNODE * 4);
  (void)ws_size; (void)n_in; (void)in_sizes; (void)out_size;

  // 1. zero accumulators
  zero_kernel<<<64, 256, 0, stream>>>((int4*)d_ws, (int)(zbytes / 16));
  // 2. HEAD: t2k || cnt2 || skip0@W0 (one launch; atomics+GEMM hide under HBM stream)
  head_kernel<<<5632, 256, 0, stream>>>(skip2, F2t, skip1, F1t,
                                        labels, edst, segb, packed, cnt_e,
                                        skip0, W0, F0b);
  // 3. FUSED-B: dual scan || rcnt/centroids
  fusedB_kernel<<<10, 1024, 0, stream>>>(packed, cnt_e, poff, eoff, rcnt, pch, pcw);
  // 4. scatter2 (pixel CSR + edge attr/CSR; writes edge_attr output)
  scatter2_kernel<<<2048 + 512, 256, 0, stream>>>(segb, poff, pcur, psorted,
                                                  esrc, edst, pch, pcw, eoff, ecur, evw, outp);
  // 5. FUSED-C: gather2(half0) -> gather01 -> gather2(half1)
  fusedC_kernel<<<24576, 256, 0, stream>>>(F0b, F1t, F2t, poff, psorted, rcnt,
                                           h0b, p1buf, p2buf);
  // 6. layer0 aggregate (h0 f16) -> x1
  agg_kernel<<<NNODE / 2, 256, 0, stream>>>(h0b, b0, eoff, evw, bufB);
  // 7-8. layer1 (mix fused into GEMM, f16 h out)
  gemm_mix_n256<<<NNODE / 16, 256, 0, stream>>>(bufB, p1buf, W1, h1b);
  agg_kernel<<<NNODE / 2, 256, 0, stream>>>(h1b, b1, eoff, evw, bufA);
  // 9. layer2 GEMM
  gemm_mix_n256<<<NNODE / 16, 256, 0, stream>>>(bufA, p2buf, W2, h1b);
  // 10. final aggregate + in-block score
  agg_score_kernel<<<NNODE / 2, 256, 0, stream>>>(h1b, b2, eoff, evw, lw, sbuf);
  // 11. dan / dap
  out_kernel<<<EE / 256, 256, 0, stream>>>(sbuf, esrc, edst, negs, outp);
}